// Round 8
// baseline (151.147 us; speedup 1.0000x reference)
//
#include <hip/hip_runtime.h>
#include <hip/hip_bf16.h>

// ExplicitInterClassGraphLoss on MI355X (gfx950)
//   loss = mean_{i,j} (fn_i . fn_j - zg[lbl_i, lbl_j])^2,  fn = row-normalized feat
// R8: LDS-pipe relief. B-fragments now load DIRECTLY from global (L2-resident
// 8 MB fn) into VGPRs each K-tile — no Bs staging, halving LDS read traffic
// (the measured binding resource, ~12cyc/ds_read_b128 through one pipe/CU).
// A keeps LDS staging: chunk-XOR swizzle + double buffer + depth-1 prefetch.
// R6's lgkm drain + setprio restored (R7 A/B showed they help). 128x128 tile
// pairs (2080), 4 waves of 64x64, zd[|li-lj|] table, XCD swizzle.

typedef __attribute__((ext_vector_type(8))) short bf16x8;
typedef __attribute__((ext_vector_type(4))) float f32x4;

#define NROW 8192
#define DIM  512
#define NBIN 40
#define NBLK 64                    // 8192 / 128
#define NPAIR (NBLK*(NBLK+1)/2)    // 2080
#define BK 32
#define NT (DIM/BK)                // 16 K-tiles
#define TELEM (128*BK)             // 4096 elems = 8 KiB per A tile buffer

__device__ __forceinline__ unsigned short f2bf(float x) {
  __hip_bfloat16 h = __float2bfloat16(x);
  union { __hip_bfloat16 h; unsigned short u; } cv;
  cv.h = h;
  return cv.u;
}

// ---------------- kernel 1: row L2-normalize, fp32 -> bf16 ----------------
__global__ __launch_bounds__(256) void rownorm_kernel(const float* __restrict__ feat,
                                                      __hip_bfloat16* __restrict__ fn) {
  int wid  = threadIdx.x >> 6;
  int lane = threadIdx.x & 63;
  int row  = blockIdx.x * 4 + wid;
  const float4* src = (const float4*)(feat + (size_t)row * DIM);
  float4 a = src[lane];
  float4 b = src[lane + 64];
  float s = a.x*a.x + a.y*a.y + a.z*a.z + a.w*a.w
          + b.x*b.x + b.y*b.y + b.z*b.z + b.w*b.w;
#pragma unroll
  for (int off = 1; off < 64; off <<= 1) s += __shfl_xor(s, off, 64);
  float scale = 1.0f / fmaxf(sqrtf(s), 1e-8f);
  ushort4 o0, o1;
  o0.x = f2bf(a.x * scale); o0.y = f2bf(a.y * scale);
  o0.z = f2bf(a.z * scale); o0.w = f2bf(a.w * scale);
  o1.x = f2bf(b.x * scale); o1.y = f2bf(b.y * scale);
  o1.z = f2bf(b.z * scale); o1.w = f2bf(b.w * scale);
  ushort4* dst = (ushort4*)(fn + (size_t)row * DIM);
  dst[lane]      = o0;
  dst[lane + 64] = o1;
}

// ---------------- kernel 2: fused loss over one 128x128 tile pair ----------------
__global__ __launch_bounds__(256, 4) void loss_kernel(const __hip_bfloat16* __restrict__ fn,
                                                      const int* __restrict__ label,
                                                      double* __restrict__ partials) {
  __shared__ __hip_bfloat16 Abuf[2][TELEM];   // 2 x 8 KiB (A only)
  __shared__ float zd[NBIN];                  // zd[d] = clip(cos(d*pi/2/39),0,1)
  __shared__ int   lbl[256];
  __shared__ float wsum[4];

  const int tid  = threadIdx.x;
  const int wid  = tid >> 6;
  const int lane = tid & 63;
  const int wr   = wid >> 1;   // 0..1 -> 64-row slab (A)
  const int wc   = wid & 1;    // 0..1 -> 64-col slab (B)

  // XCD-aware swizzle: 2080 = 8 * 260 exactly -> bijective
  const int t0 = (blockIdx.x & 7) * (NPAIR / 8) + (blockIdx.x >> 3);

  // upper-triangular pair map (bi <= bj)
  int bi = 0;
  while (bi < NBLK - 1 && (bi + 1) * NBLK - ((bi + 1) * bi) / 2 <= t0) bi++;
  const int bj = bi + (t0 - (bi * NBLK - (bi * (bi - 1)) / 2));
  const int i0 = bi * 128;
  const int j0 = bj * 128;

  // 40-entry distance table + labels
  if (tid < NBIN) {
    float d = (float)tid * (float)(1.5707963267948966 / (NBIN - 1));
    zd[tid] = fminf(fmaxf(cosf(d), 0.0f), 1.0f);
  }
  lbl[tid] = (tid < 128) ? label[i0 + tid] : label[j0 + tid - 128];

  // A staging geometry: tile = 128 rows x 32 cols = 512 16B-chunks; 2/thread.
  // LDS chunk L -> (row=L>>2, c=L&3); slot holds global chunk c ^ ((row>>1)&3)
  // (involution; read side applies same XOR). Dest linear in lane order.
  const __hip_bfloat16* srcA[2];
  int dstOff[2];
#pragma unroll
  for (int q = 0; q < 2; ++q) {
    const int L   = q * 256 + tid;
    const int row = L >> 2;
    const int cg  = (L & 3) ^ ((row >> 1) & 3);
    srcA[q] = fn + (size_t)(i0 + row) * DIM + cg * 8;
    dstOff[q] = (q * 256 + wid * 64) * 16;   // bytes; wave-uniform base
  }

  auto issueA = [&](int tt, int bb) {
#pragma unroll
    for (int q = 0; q < 2; ++q)
      __builtin_amdgcn_global_load_lds(
          (const __attribute__((address_space(1))) void*)(srcA[q] + tt * BK),
          (__attribute__((address_space(3))) void*)((char*)&Abuf[bb][0] + dstOff[q]),
          16, 0, 0);
  };

  const int fr = lane & 15;                 // fragment row-in-16
  const int fc = lane >> 4;                 // fragment k-chunk 0..3
  const int cx = fc ^ ((fr >> 1) & 3);      // swizzled chunk (LDS read side)
  const int arow0 = wr * 64 + fr;

  // B fragment base in GLOBAL memory (no swizzle): row = j0+wc*64+fr (+n*16),
  // col = fc*8 (+t*32). Frag n load = one global_load_dwordx4 per lane.
  const __hip_bfloat16* bbase = fn + (size_t)(j0 + wc * 64 + fr) * DIM + fc * 8;

  // ---- prologue: A tile 0 into buf 0 ----
  issueA(0, 0);
  asm volatile("s_waitcnt vmcnt(0)" ::: "memory");
  __builtin_amdgcn_s_barrier();

  f32x4 acc[4][4] = {};

  for (int t = 0; t < NT; ++t) {
    const int c = t & 1;
    const __hip_bfloat16* Ab = &Abuf[c][0];

    // B frags direct from global (compiler inserts exact vmcnt before MFMA use)
    bf16x8 bf[4];
#pragma unroll
    for (int n = 0; n < 4; ++n)
      bf[n] = *(const bf16x8*)(bbase + (size_t)n * 16 * DIM + t * BK);

    // A frags from LDS (swizzled)
    bf16x8 af[4];
#pragma unroll
    for (int m = 0; m < 4; ++m)
      af[m] = *(const bf16x8*)&Ab[(arow0 + m * 16) * BK + cx * 8];

    if (t < NT - 1) issueA(t + 1, c ^ 1);   // depth-1 A prefetch into other buffer

    asm volatile("s_waitcnt lgkmcnt(0)" ::: "memory");
    __builtin_amdgcn_s_setprio(1);
#pragma unroll
    for (int m = 0; m < 4; ++m)
#pragma unroll
      for (int n = 0; n < 4; ++n)
        acc[m][n] = __builtin_amdgcn_mfma_f32_16x16x32_bf16(af[m], bf[n], acc[m][n], 0, 0, 0);
    __builtin_amdgcn_s_setprio(0);

    if (t < NT - 1) {
      asm volatile("s_waitcnt vmcnt(0)" ::: "memory");  // A(t+1) landed (hidden under MFMA)
      __builtin_amdgcn_s_barrier();                     // block-wide visibility
    }
  }

  // ---- epilogue: diff vs zd[|li-lj|], sum of squares ----
  // C/D mapping (m89): col = lane&15, row = (lane>>4)*4 + r. Transpose-safe
  // (both matrices symmetric).
  const int rb4 = (lane >> 4) * 4;
  int ljv[4];
#pragma unroll
  for (int n = 0; n < 4; ++n) ljv[n] = lbl[128 + wc * 64 + n * 16 + fr];
  float lsum = 0.0f;
#pragma unroll
  for (int m = 0; m < 4; ++m) {
#pragma unroll
    for (int r = 0; r < 4; ++r) {
      const int li = lbl[wr * 64 + m * 16 + rb4 + r];
#pragma unroll
      for (int n = 0; n < 4; ++n) {
        int dd = li - ljv[n]; if (dd < 0) dd = -dd;
        float d = acc[m][n][r] - zd[dd];
        lsum += d * d;
      }
    }
  }
  if (bi != bj) lsum *= 2.0f;   // off-diagonal tile counted twice

#pragma unroll
  for (int off = 1; off < 64; off <<= 1) lsum += __shfl_xor(lsum, off, 64);
  if (lane == 0) wsum[wid] = lsum;
  __syncthreads();
  if (tid == 0)
    partials[blockIdx.x] = (double)((wsum[0] + wsum[1]) + (wsum[2] + wsum[3]));
}

// ---------------- kernel 3: finalize ----------------
__global__ __launch_bounds__(256) void finalize_kernel(const double* __restrict__ partials,
                                                       int nblk, float* __restrict__ out) {
  __shared__ double wsh[4];
  int wid = threadIdx.x >> 6, lane = threadIdx.x & 63;
  double s = 0.0;
  for (int i = threadIdx.x; i < nblk; i += 256) s += partials[i];
#pragma unroll
  for (int off = 1; off < 64; off <<= 1) s += __shfl_xor(s, off, 64);
  if (lane == 0) wsh[wid] = s;
  __syncthreads();
  if (threadIdx.x == 0) {
    double tot = wsh[0] + wsh[1] + wsh[2] + wsh[3];
    out[0] = (float)(tot / ((double)NROW * (double)NROW));
  }
}

extern "C" void kernel_launch(void* const* d_in, const int* in_sizes, int n_in,
                              void* d_out, int out_size, void* d_ws, size_t ws_size,
                              hipStream_t stream) {
  const int*   label = (const int*)d_in[0];    // (8192,) int32
  const float* feat  = (const float*)d_in[1];  // (8192, 512) fp32
  float* out = (float*)d_out;

  char* ws = (char*)d_ws;
  __hip_bfloat16* fn = (__hip_bfloat16*)ws;                       // 8 MiB
  double* partials = (double*)(ws + (size_t)NROW * DIM * 2);      // NPAIR doubles

  rownorm_kernel<<<NROW / 4, 256, 0, stream>>>(feat, fn);
  loss_kernel<<<NPAIR, 256, 0, stream>>>(fn, label, partials);
  finalize_kernel<<<1, 256, 0, stream>>>(partials, NPAIR, out);
}

// Round 11
// 116.062 us; speedup vs baseline: 1.3023x; 1.3023x over previous
//
#include <hip/hip_runtime.h>
#include <hip/hip_bf16.h>

// ExplicitInterClassGraphLoss on MI355X (gfx950)
//   loss = mean_{i,j} (fn_i . fn_j - zg[lbl_i, lbl_j])^2,  fn = row-normalized feat
// R10 = R9b resubmitted (infra timeout, no measurement).
// Register-pipelined K-loop + hardened boundary fences. Per tile t:
//   MFMA uses frags(t) preloaded in regs || ds_read frags(t+1) from
//   buf[(t+1)%3] || issue global_load_lds for tile t+3 into buf[t%3].
//   Boundary: vmcnt(4) [t+2 landed, t+3 in flight] + lgkmcnt(0) [ALL waves'
//   frag reads retired before anyone crosses] + s_barrier.
// WAR proof: buf[t%3]'s readers (frags(t), read during BODY(t-1)) retire
// before the end-of-BODY(t-1) lgkm0+barrier; BODY(t)'s G-issue is after it.
// Prologue equivalently fenced after frag(0) loads.
// Keeps: chunk-XOR LDS swizzle, zd[|li-lj|] table, XCD swizzle, upper-tri x2.

typedef __attribute__((ext_vector_type(8))) short bf16x8;
typedef __attribute__((ext_vector_type(4))) float f32x4;

#define NROW 8192
#define DIM  512
#define NBIN 40
#define NBLK 64                    // 8192 / 128
#define NPAIR (NBLK*(NBLK+1)/2)    // 2080
#define BK 32
#define NT (DIM/BK)                // 16 K-tiles
#define TELEM (128*BK)             // 4096 elems = 8 KiB per tile buffer

__device__ __forceinline__ unsigned short f2bf(float x) {
  __hip_bfloat16 h = __float2bfloat16(x);
  union { __hip_bfloat16 h; unsigned short u; } cv;
  cv.h = h;
  return cv.u;
}

// ---------------- kernel 1: row L2-normalize, fp32 -> bf16 ----------------
__global__ __launch_bounds__(256) void rownorm_kernel(const float* __restrict__ feat,
                                                      __hip_bfloat16* __restrict__ fn) {
  int wid  = threadIdx.x >> 6;
  int lane = threadIdx.x & 63;
  int row  = blockIdx.x * 4 + wid;
  const float4* src = (const float4*)(feat + (size_t)row * DIM);
  float4 a = src[lane];
  float4 b = src[lane + 64];
  float s = a.x*a.x + a.y*a.y + a.z*a.z + a.w*a.w
          + b.x*b.x + b.y*b.y + b.z*b.z + b.w*b.w;
#pragma unroll
  for (int off = 1; off < 64; off <<= 1) s += __shfl_xor(s, off, 64);
  float scale = 1.0f / fmaxf(sqrtf(s), 1e-8f);
  ushort4 o0, o1;
  o0.x = f2bf(a.x * scale); o0.y = f2bf(a.y * scale);
  o0.z = f2bf(a.z * scale); o0.w = f2bf(a.w * scale);
  o1.x = f2bf(b.x * scale); o1.y = f2bf(b.y * scale);
  o1.z = f2bf(b.z * scale); o1.w = f2bf(b.w * scale);
  ushort4* dst = (ushort4*)(fn + (size_t)row * DIM);
  dst[lane]      = o0;
  dst[lane + 64] = o1;
}

// ---------------- kernel 2: fused loss over one 128x128 tile pair ----------------
__global__ __launch_bounds__(256, 3) void loss_kernel(const __hip_bfloat16* __restrict__ fn,
                                                      const int* __restrict__ label,
                                                      double* __restrict__ partials) {
  __shared__ __hip_bfloat16 Abuf[3][TELEM];   // 3 x 8 KiB
  __shared__ __hip_bfloat16 Bbuf[3][TELEM];   // 3 x 8 KiB
  __shared__ float zd[NBIN];
  __shared__ int   lbl[256];
  __shared__ float wsum[4];

  const int tid  = threadIdx.x;
  const int wid  = tid >> 6;
  const int lane = tid & 63;
  const int wr   = wid >> 1;   // 0..1 -> 64-row slab
  const int wc   = wid & 1;    // 0..1 -> 64-col slab

  // XCD-aware swizzle: 2080 = 8 * 260 -> bijective
  const int t0 = (blockIdx.x & 7) * (NPAIR / 8) + (blockIdx.x >> 3);

  // upper-triangular pair map (bi <= bj)
  int bi = 0;
  while (bi < NBLK - 1 && (bi + 1) * NBLK - ((bi + 1) * bi) / 2 <= t0) bi++;
  const int bj = bi + (t0 - (bi * NBLK - (bi * (bi - 1)) / 2));
  const int i0 = bi * 128;
  const int j0 = bj * 128;

  // zd table (VALU only) + labels
  if (tid < NBIN) {
    float d = (float)tid * (float)(1.5707963267948966 / (NBIN - 1));
    zd[tid] = fminf(fmaxf(cosf(d), 0.0f), 1.0f);
  }
  lbl[tid] = (tid < 128) ? label[i0 + tid] : label[j0 + tid - 128];
  // drain the lbl global load so staging vmcnt counts are exact
  asm volatile("s_waitcnt vmcnt(0)" ::: "memory");

  // staging geometry (as R6): tile = 128x32 = 512 16B-chunks; 2/thread.
  // LDS chunk L -> (row=L>>2, c=L&3); slot holds global chunk c ^ ((row>>1)&3).
  const __hip_bfloat16* srcA[2];
  const __hip_bfloat16* srcB[2];
  int dstOff[2];
#pragma unroll
  for (int q = 0; q < 2; ++q) {
    const int L   = q * 256 + tid;
    const int row = L >> 2;
    const int cg  = (L & 3) ^ ((row >> 1) & 3);
    srcA[q] = fn + (size_t)(i0 + row) * DIM + cg * 8;
    srcB[q] = fn + (size_t)(j0 + row) * DIM + cg * 8;
    dstOff[q] = (q * 256 + wid * 64) * 16;
  }

  auto issueTile = [&](int tt, int bb) {
#pragma unroll
    for (int q = 0; q < 2; ++q)
      __builtin_amdgcn_global_load_lds(
          (const __attribute__((address_space(1))) void*)(srcA[q] + tt * BK),
          (__attribute__((address_space(3))) void*)((char*)&Abuf[bb][0] + dstOff[q]),
          16, 0, 0);
#pragma unroll
    for (int q = 0; q < 2; ++q)
      __builtin_amdgcn_global_load_lds(
          (const __attribute__((address_space(1))) void*)(srcB[q] + tt * BK),
          (__attribute__((address_space(3))) void*)((char*)&Bbuf[bb][0] + dstOff[q]),
          16, 0, 0);
  };

  const int fr = lane & 15;
  const int fc = lane >> 4;
  const int cx = fc ^ ((fr >> 1) & 3);      // swizzled chunk (read side)
  const int arow0 = wr * 64 + fr;
  const int brow0 = wc * 64 + fr;

  // ---- prologue: tiles 0,1,2 in flight; guarantee 0 and 1 ----
  issueTile(0, 0); issueTile(1, 1); issueTile(2, 2);
  asm volatile("s_waitcnt vmcnt(4)" ::: "memory");   // G0+G1 landed, G2 in flight
  __builtin_amdgcn_s_barrier();                      // publish G0,G1 block-wide

  f32x4 acc[4][4] = {};
  bf16x8 afX[4], bfX[4], afY[4], bfY[4];             // two named frag sets

  // load frags(0) into set X
#pragma unroll
  for (int m = 0; m < 4; ++m)
    afX[m] = *(const bf16x8*)&Abuf[0][(arow0 + m * 16) * BK + cx * 8];
#pragma unroll
  for (int n = 0; n < 4; ++n)
    bfX[n] = *(const bf16x8*)&Bbuf[0][(brow0 + n * 16) * BK + cx * 8];
  // block-wide retire of frag(0) reads BEFORE BODY(0) can overwrite buf0
  asm volatile("s_waitcnt lgkmcnt(0)" ::: "memory");
  __builtin_amdgcn_s_barrier();

#define BODY(T, AC, BC, AN, BN)                                                  \
  {                                                                              \
    const int t_ = (T);                                                          \
    if (t_ + 3 < NT) issueTile(t_ + 3, t_ % 3);                                  \
    if (t_ + 1 < NT) {                                                           \
      const int b1 = (t_ + 1) % 3;                                               \
      _Pragma("unroll")                                                          \
      for (int m = 0; m < 4; ++m)                                                \
        AN[m] = *(const bf16x8*)&Abuf[b1][(arow0 + m * 16) * BK + cx * 8];       \
      _Pragma("unroll")                                                          \
      for (int n = 0; n < 4; ++n)                                                \
        BN[n] = *(const bf16x8*)&Bbuf[b1][(brow0 + n * 16) * BK + cx * 8];       \
    }                                                                            \
    __builtin_amdgcn_s_setprio(1);                                               \
    _Pragma("unroll")                                                            \
    for (int m = 0; m < 4; ++m)                                                  \
      _Pragma("unroll")                                                          \
      for (int n = 0; n < 4; ++n)                                                \
        acc[m][n] = __builtin_amdgcn_mfma_f32_16x16x32_bf16(AC[m], BC[n],        \
                                                            acc[m][n], 0, 0, 0); \
    __builtin_amdgcn_s_setprio(0);                                               \
    if (t_ < NT - 1) {                                                           \
      if (t_ < NT - 3) asm volatile("s_waitcnt vmcnt(4)" ::: "memory");          \
      else             asm volatile("s_waitcnt vmcnt(0)" ::: "memory");          \
      /* block-wide retire of this body's frag reads before next overwrite */    \
      asm volatile("s_waitcnt lgkmcnt(0)" ::: "memory");                         \
      __builtin_amdgcn_s_barrier();                                              \
    }                                                                            \
  }

  for (int t = 0; t < NT; t += 2) {
    BODY(t,     afX, bfX, afY, bfY);
    BODY(t + 1, afY, bfY, afX, bfX);
  }
#undef BODY

  // ---- epilogue: diff vs zd[|li-lj|], sum of squares ----
  // C/D mapping (m89): col = lane&15, row = (lane>>4)*4 + r. Transpose-safe.
  const int rb4 = (lane >> 4) * 4;
  int ljv[4];
#pragma unroll
  for (int n = 0; n < 4; ++n) ljv[n] = lbl[128 + wc * 64 + n * 16 + fr];
  float lsum = 0.0f;
#pragma unroll
  for (int m = 0; m < 4; ++m) {
#pragma unroll
    for (int r = 0; r < 4; ++r) {
      const int li = lbl[wr * 64 + m * 16 + rb4 + r];
#pragma unroll
      for (int n = 0; n < 4; ++n) {
        int dd = li - ljv[n]; if (dd < 0) dd = -dd;
        float d = acc[m][n][r] - zd[dd];
        lsum += d * d;
      }
    }
  }
  if (bi != bj) lsum *= 2.0f;   // off-diagonal tile counted twice

#pragma unroll
  for (int off = 1; off < 64; off <<= 1) lsum += __shfl_xor(lsum, off, 64);
  if (lane == 0) wsum[wid] = lsum;
  __syncthreads();
  if (tid == 0)
    partials[blockIdx.x] = (double)((wsum[0] + wsum[1]) + (wsum[2] + wsum[3]));
}

// ---------------- kernel 3: finalize ----------------
__global__ __launch_bounds__(256) void finalize_kernel(const double* __restrict__ partials,
                                                       int nblk, float* __restrict__ out) {
  __shared__ double wsh[4];
  int wid = threadIdx.x >> 6, lane = threadIdx.x & 63;
  double s = 0.0;
  for (int i = threadIdx.x; i < nblk; i += 256) s += partials[i];
#pragma unroll
  for (int off = 1; off < 64; off <<= 1) s += __shfl_xor(s, off, 64);
  if (lane == 0) wsh[wid] = s;
  __syncthreads();
  if (threadIdx.x == 0) {
    double tot = wsh[0] + wsh[1] + wsh[2] + wsh[3];
    out[0] = (float)(tot / ((double)NROW * (double)NROW));
  }
}

extern "C" void kernel_launch(void* const* d_in, const int* in_sizes, int n_in,
                              void* d_out, int out_size, void* d_ws, size_t ws_size,
                              hipStream_t stream) {
  const int*   label = (const int*)d_in[0];    // (8192,) int32
  const float* feat  = (const float*)d_in[1];  // (8192, 512) fp32
  float* out = (float*)d_out;

  char* ws = (char*)d_ws;
  __hip_bfloat16* fn = (__hip_bfloat16*)ws;                       // 8 MiB
  double* partials = (double*)(ws + (size_t)NROW * DIM * 2);      // NPAIR doubles

  rownorm_kernel<<<NROW / 4, 256, 0, stream>>>(feat, fn);
  loss_kernel<<<NPAIR, 256, 0, stream>>>(fn, label, partials);
  finalize_kernel<<<1, 256, 0, stream>>>(partials, NPAIR, out);
}